// Round 1
// 5563.284 us; speedup vs baseline: 1.3445x; 1.3445x over previous
//
#include <hip/hip_runtime.h>
#include <hip/hip_bf16.h>
#include <math.h>

// Problem constants
#define Vv 50257
#define Tt 512
#define Dd 512
#define Hh 8
#define Ll 6
#define Bb 4
#define HD 64
#define ROWS (Bb * Tt)   // 2048

// ---------------------------------------------------------------------------
// Embedding: h[b,t,:] = tok_emb[x[b,t],:] + pos_emb[t,:]
// ---------------------------------------------------------------------------
__global__ __launch_bounds__(256) void embed_kernel(
    const int* __restrict__ x, const float* __restrict__ tok,
    const float* __restrict__ pos, float* __restrict__ h)
{
    int row = blockIdx.x;          // b*T + t
    int t = row & (Tt - 1);
    int tid = threadIdx.x;
    int id = x[row];
    size_t ro = (size_t)row * Dd;
    size_t eo = (size_t)id * Dd;
    size_t po = (size_t)t * Dd;
    h[ro + tid]       = tok[eo + tid]       + pos[po + tid];
    h[ro + tid + 256] = tok[eo + tid + 256] + pos[po + tid + 256];
}

// ---------------------------------------------------------------------------
// LayerNorm: one block per row, D=512, 256 threads (2 elems/thread)
// ---------------------------------------------------------------------------
__global__ __launch_bounds__(256) void ln_kernel(
    const float* __restrict__ in, const float* __restrict__ s,
    const float* __restrict__ b, float* __restrict__ out)
{
    int row = blockIdx.x;
    int tid = threadIdx.x;
    const float* xp = in + (size_t)row * Dd;
    float v0 = xp[tid], v1 = xp[tid + 256];
    float sum = v0 + v1;
    float sq  = v0 * v0 + v1 * v1;
    // wave (64-lane) reduce
    #pragma unroll
    for (int off = 32; off; off >>= 1) {
        sum += __shfl_down(sum, off);
        sq  += __shfl_down(sq,  off);
    }
    __shared__ float rsum[4], rsq[4], stats[2];
    int lane = tid & 63, wid = tid >> 6;
    if (lane == 0) { rsum[wid] = sum; rsq[wid] = sq; }
    __syncthreads();
    if (tid == 0) {
        float ts = rsum[0] + rsum[1] + rsum[2] + rsum[3];
        float tq = rsq[0] + rsq[1] + rsq[2] + rsq[3];
        float m = ts * (1.0f / Dd);
        float var = tq * (1.0f / Dd) - m * m;
        stats[0] = m;
        stats[1] = rsqrtf(var + 1e-5f);
    }
    __syncthreads();
    float m = stats[0], rstd = stats[1];
    float* op = out + (size_t)row * Dd;
    op[tid]       = (v0 - m) * rstd * s[tid]       + b[tid];
    op[tid + 256] = (v1 - m) * rstd * s[tid + 256] + b[tid + 256];
}

__device__ __forceinline__ float gelu_f(float v)
{
    return 0.5f * v * (1.0f + erff(v * 0.70710678118654752f));
}

// ---------------------------------------------------------------------------
// Tiled fp32 GEMM v2: C[M,N] = A[M,K] @ B[K,N] + bias[N] (+GELU) (+residual)
// 64(M) x 128(N) tile, BK=16, 256 threads, 4x8 per thread.
// - ds_read_b128 fragment loads (A broadcast, B 2-way free)
// - As padded to stride 68 (2-way-free transposed stores, aligned b128 reads)
// - register prefetch of next k-tile under compute
// - vector B-staging / C-store when N%4==0 (all layer GEMMs); guarded scalar
//   path for the head GEMM (N=50257, odd -> rows not 16B aligned)
// - grid: x = M tiles (32), y = N tiles -> concurrent blocks share B panels
// ---------------------------------------------------------------------------
template<bool GELU, bool RES>
__global__ __launch_bounds__(256) void gemm_kernel(
    const float* __restrict__ A, const float* __restrict__ Bm,
    const float* __restrict__ bias, const float* __restrict__ res,
    float* __restrict__ C, int M, int N, int K)
{
    __shared__ float As[16][68];    // [k][m], stride 68 floats (272B = 17*16)
    __shared__ float Bs[16][128];   // [k][n]

    const int tid = threadIdx.x;
    const int block_row = blockIdx.x * 64;
    const int block_col = blockIdx.y * 128;

    const int tx = tid & 15;        // n-fragment: cols tx*4..+3 and 64+tx*4..+3
    const int ty = tid >> 4;        // m-fragment: rows ty*4..+3 (0..15)

    // A staging: m = tid>>2 (0..63), kb = (tid&3)*4 -> one float4 along K
    const int sa_m = tid >> 2;
    const int sa_k = (tid & 3) << 2;
    // B staging (vector, N%4==0): c = (tid&31)*4, rows kr and kr+8
    const int sbv_c = (tid & 31) << 2;
    const int sbv_k = tid >> 5;
    // B staging (scalar, ragged N): c = tid&127, rows kr+2p
    const int sbs_c = tid & 127;
    const int sbs_k = tid >> 7;

    const bool nvec = ((N & 3) == 0);

    const float* Arow = A + (size_t)(block_row + sa_m) * K + sa_k;

    float areg[4];
    float breg[8];

    // ---- tile loader (global -> registers) ----
    auto load_tile = [&](int k0) {
        const float4 av = *(const float4*)(Arow + k0);
        areg[0] = av.x; areg[1] = av.y; areg[2] = av.z; areg[3] = av.w;
        if (nvec) {
            const float4 b0 = *(const float4*)(Bm + (size_t)(k0 + sbv_k) * N + block_col + sbv_c);
            const float4 b1 = *(const float4*)(Bm + (size_t)(k0 + sbv_k + 8) * N + block_col + sbv_c);
            breg[0] = b0.x; breg[1] = b0.y; breg[2] = b0.z; breg[3] = b0.w;
            breg[4] = b1.x; breg[5] = b1.y; breg[6] = b1.z; breg[7] = b1.w;
        } else {
            int gc = block_col + sbs_c;
            #pragma unroll
            for (int p = 0; p < 8; ++p) {
                float v = 0.f;
                if (gc < N) v = Bm[(size_t)(k0 + sbs_k + 2 * p) * N + gc];
                breg[p] = v;
            }
        }
    };
    // ---- tile writer (registers -> LDS) ----
    auto store_tile = [&]() {
        #pragma unroll
        for (int j = 0; j < 4; ++j) As[sa_k + j][sa_m] = areg[j];
        if (nvec) {
            *(float4*)&Bs[sbv_k][sbv_c]     = make_float4(breg[0], breg[1], breg[2], breg[3]);
            *(float4*)&Bs[sbv_k + 8][sbv_c] = make_float4(breg[4], breg[5], breg[6], breg[7]);
        } else {
            #pragma unroll
            for (int p = 0; p < 8; ++p) Bs[sbs_k + 2 * p][sbs_c] = breg[p];
        }
    };

    float acc[4][8] = {};

    const int nk = K >> 4;
    load_tile(0);
    for (int t = 0; t < nk; ++t) {
        store_tile();
        __syncthreads();
        if (t + 1 < nk) load_tile((t + 1) << 4);
        #pragma unroll
        for (int kk = 0; kk < 16; ++kk) {
            const float4 a  = *(const float4*)&As[kk][ty * 4];
            const float4 b0 = *(const float4*)&Bs[kk][tx * 4];
            const float4 b1 = *(const float4*)&Bs[kk][64 + tx * 4];
            const float av[4] = {a.x, a.y, a.z, a.w};
            const float bv[8] = {b0.x, b0.y, b0.z, b0.w, b1.x, b1.y, b1.z, b1.w};
            #pragma unroll
            for (int i = 0; i < 4; ++i)
                #pragma unroll
                for (int j = 0; j < 8; ++j)
                    acc[i][j] += av[i] * bv[j];
        }
        __syncthreads();
    }

    // ---- epilogue ----
    #pragma unroll
    for (int i = 0; i < 4; ++i) {
        int row = block_row + ty * 4 + i;
        if (row >= M) continue;
        size_t rb = (size_t)row * N;
        if (nvec) {
            #pragma unroll
            for (int hf = 0; hf < 2; ++hf) {
                int col = block_col + hf * 64 + tx * 4;
                float4 v;
                v.x = acc[i][hf * 4 + 0] + bias[col + 0];
                v.y = acc[i][hf * 4 + 1] + bias[col + 1];
                v.z = acc[i][hf * 4 + 2] + bias[col + 2];
                v.w = acc[i][hf * 4 + 3] + bias[col + 3];
                if (GELU) {
                    v.x = gelu_f(v.x); v.y = gelu_f(v.y);
                    v.z = gelu_f(v.z); v.w = gelu_f(v.w);
                }
                if (RES) {
                    const float4 r = *(const float4*)(res + rb + col);
                    v.x += r.x; v.y += r.y; v.z += r.z; v.w += r.w;
                }
                *(float4*)(C + rb + col) = v;
            }
        } else {
            #pragma unroll
            for (int jj = 0; jj < 8; ++jj) {
                int col = block_col + (jj >> 2) * 64 + tx * 4 + (jj & 3);
                if (col < N) {
                    float v = acc[i][jj] + bias[col];
                    if (GELU) v = gelu_f(v);
                    if (RES) v += res[rb + col];
                    C[rb + col] = v;
                }
            }
        }
    }
}

// ---------------------------------------------------------------------------
// Fused attention: one block per (b, h, query row i).
// scores (causal) -> softmax -> @V. qkv layout: [B*T, 3*D], q|k|v slabs.
// ---------------------------------------------------------------------------
__global__ __launch_bounds__(256) void attn_kernel(
    const float* __restrict__ qkv, float* __restrict__ att)
{
    int idx = blockIdx.x;
    int i = idx & (Tt - 1);
    int h = (idx >> 9) & (Hh - 1);
    int b = idx >> 12;
    int tid = threadIdx.x;

    __shared__ float qs[HD];
    __shared__ float ps[Tt];
    __shared__ float red[8];
    __shared__ float opart[256];

    const size_t base = (size_t)(b * Tt) * (3 * Dd);
    if (tid < HD) qs[tid] = qkv[base + (size_t)i * (3 * Dd) + h * HD + tid];
    __syncthreads();

    // scores + row max
    float lmax = -INFINITY;
    for (int j = tid; j < Tt; j += 256) {
        float sc = -INFINITY;
        if (j <= i) {
            const float* krow = qkv + base + (size_t)j * (3 * Dd) + Dd + h * HD;
            float dot = 0.f;
            #pragma unroll
            for (int d = 0; d < HD; ++d) dot += qs[d] * krow[d];
            sc = dot * 0.125f;   // 1/sqrt(64)
        }
        ps[j] = sc;
        lmax = fmaxf(lmax, sc);
    }
    #pragma unroll
    for (int off = 32; off; off >>= 1) lmax = fmaxf(lmax, __shfl_down(lmax, off));
    int lane = tid & 63, wid = tid >> 6;
    if (lane == 0) red[wid] = lmax;
    __syncthreads();
    if (tid == 0)
        red[4] = fmaxf(fmaxf(red[0], red[1]), fmaxf(red[2], red[3]));
    __syncthreads();
    float m = red[4];

    // exp + row sum
    float lsum = 0.f;
    for (int j = tid; j < Tt; j += 256) {
        float e = (j <= i) ? expf(ps[j] - m) : 0.f;
        ps[j] = e;
        lsum += e;
    }
    #pragma unroll
    for (int off = 32; off; off >>= 1) lsum += __shfl_down(lsum, off);
    if (lane == 0) red[wid] = lsum;
    __syncthreads();
    if (tid == 0) red[4] = red[0] + red[1] + red[2] + red[3];
    __syncthreads();
    float Z = red[4];

    // O = (p @ V) / Z ; thread = (jc, d), 4 j-chunks x 64 dims
    int d = tid & 63;
    int jc = tid >> 6;
    float acc = 0.f;
    for (int j = jc; j <= i; j += 4)
        acc += ps[j] * qkv[base + (size_t)j * (3 * Dd) + 2 * Dd + h * HD + d];
    opart[tid] = acc;
    __syncthreads();
    if (tid < 64) {
        float o = (opart[tid] + opart[tid + 64] + opart[tid + 128] + opart[tid + 192]) / Z;
        att[(size_t)(b * Tt + i) * Dd + h * HD + tid] = o;
    }
}

// ---------------------------------------------------------------------------
// Launch
// ---------------------------------------------------------------------------
extern "C" void kernel_launch(void* const* d_in, const int* in_sizes, int n_in,
                              void* d_out, int out_size, void* d_ws, size_t ws_size,
                              hipStream_t stream)
{
    const int*   x       = (const int*)d_in[0];
    const float* tok_emb = (const float*)d_in[1];
    const float* pos_emb = (const float*)d_in[2];
    const float* qkv_w   = (const float*)d_in[3];
    const float* qkv_b   = (const float*)d_in[4];
    const float* out_w   = (const float*)d_in[5];
    const float* out_b   = (const float*)d_in[6];
    const float* ln1_s   = (const float*)d_in[7];
    const float* ln1_b   = (const float*)d_in[8];
    const float* ff1_w   = (const float*)d_in[9];
    const float* ff1_b   = (const float*)d_in[10];
    const float* ff2_w   = (const float*)d_in[11];
    const float* ff2_b   = (const float*)d_in[12];
    const float* ln2_s   = (const float*)d_in[13];
    const float* ln2_b   = (const float*)d_in[14];
    const float* lnf_s   = (const float*)d_in[15];
    const float* lnf_b   = (const float*)d_in[16];
    const float* head_w  = (const float*)d_in[17];
    const float* head_b  = (const float*)d_in[18];
    float* out = (float*)d_out;

    // Workspace carve-up (floats): 40 MB total
    float* ws   = (float*)d_ws;
    float* h    = ws;                          // ROWS*D      = 1,048,576
    float* hn   = h   + (size_t)ROWS * Dd;     // ROWS*D
    float* qkvb = hn  + (size_t)ROWS * Dd;     // ROWS*3D     = 3,145,728
    float* att  = qkvb + (size_t)ROWS * 3 * Dd;// ROWS*D
    float* mid  = att + (size_t)ROWS * Dd;     // ROWS*4D     = 4,194,304

    // Embedding
    embed_kernel<<<ROWS, 256, 0, stream>>>(x, tok_emb, pos_emb, h);

    for (int l = 0; l < Ll; ++l) {
        const float* w_qkv = qkv_w + (size_t)l * Dd * 3 * Dd;
        const float* b_qkv = qkv_b + (size_t)l * 3 * Dd;
        const float* w_out = out_w + (size_t)l * Dd * Dd;
        const float* b_out = out_b + (size_t)l * Dd;
        const float* w_f1  = ff1_w + (size_t)l * Dd * 4 * Dd;
        const float* b_f1  = ff1_b + (size_t)l * 4 * Dd;
        const float* w_f2  = ff2_w + (size_t)l * 4 * Dd * Dd;
        const float* b_f2  = ff2_b + (size_t)l * Dd;

        // ln1
        ln_kernel<<<ROWS, 256, 0, stream>>>(h, ln1_s + (size_t)l * Dd,
                                            ln1_b + (size_t)l * Dd, hn);
        // qkv = hn @ w_qkv + b_qkv   [2048 x 1536]
        gemm_kernel<false, false><<<dim3(ROWS / 64, 3 * Dd / 128), 256, 0, stream>>>(
            hn, w_qkv, b_qkv, nullptr, qkvb, ROWS, 3 * Dd, Dd);
        // attention
        attn_kernel<<<Bb * Hh * Tt, 256, 0, stream>>>(qkvb, att);
        // h = att @ w_out + b_out + h
        gemm_kernel<false, true><<<dim3(ROWS / 64, Dd / 128), 256, 0, stream>>>(
            att, w_out, b_out, h, h, ROWS, Dd, Dd);
        // ln2
        ln_kernel<<<ROWS, 256, 0, stream>>>(h, ln2_s + (size_t)l * Dd,
                                            ln2_b + (size_t)l * Dd, hn);
        // mid = gelu(hn @ w_f1 + b_f1)   [2048 x 2048]
        gemm_kernel<true, false><<<dim3(ROWS / 64, 4 * Dd / 128), 256, 0, stream>>>(
            hn, w_f1, b_f1, nullptr, mid, ROWS, 4 * Dd, Dd);
        // h = mid @ w_f2 + b_f2 + h   [2048 x 512], K=2048
        gemm_kernel<false, true><<<dim3(ROWS / 64, Dd / 128), 256, 0, stream>>>(
            mid, w_f2, b_f2, h, h, ROWS, Dd, 4 * Dd);
    }

    // Final LN + head
    ln_kernel<<<ROWS, 256, 0, stream>>>(h, lnf_s, lnf_b, hn);
    // logits = hn @ head_w + head_b   [2048 x 50257]
    gemm_kernel<false, false><<<dim3(ROWS / 64, (Vv + 127) / 128), 256, 0, stream>>>(
        hn, head_w, head_b, nullptr, out, ROWS, Vv, Dd);
}